// Round 13
// baseline (122.434 us; speedup 1.0000x reference)
//
#include <hip/hip_runtime.h>

#define NN     2048
#define F0D    128
#define HIDD   64
#define OUTD   16
#define KDEG   10
#define NCHAIN 128      // chain blocks; each owns 16 L-columns, LDS-resident
#define COLS   16

typedef unsigned int u32;

// ws float layout:
//  [0]      P(j) = ws + (j-1)*2048, j=1..10 (per-round p buffers; P(10)=weff)
//  [28672]  chain flags PADDED: level j at ws+28672+(j-1)*2048, + g*16 (u32)
//           — one 64B line per producer per level (r11 proved shared flag
//           lines starve producer stores: +10us typical, 40ms outlier)
//
// A/B intent (r13): chain = r10 VERBATIM (47.0us best measured); epilogue =
// r12's distributed fold (mechanically off the chain critical path). This
// isolates the epilogue vs r10 and the chain edits vs r12 (50.6us).
//
// Sync: relaxed agent atomics only (MALL-homed, no cache maintenance).
// Producer: 16 data stores -> vmcnt(0) -> one value-tagged flag on a private
// line. Consumer: wave 0 polls, LDS-relays rdy; data read with PLAIN cached
// loads (per-j buffers are first-touch per XCD -> miss fetches MALL-fresh;
// validated r6..r12). No ws memset: value-tagged flags are poison-immune.
#define CTAG(j) (0xC0DE0000u + (u32)(j))

static __device__ __forceinline__ u32 ld_flag(const u32* p) {
    return __hip_atomic_load(p, __ATOMIC_RELAXED, __HIP_MEMORY_SCOPE_AGENT);
}
static __device__ __forceinline__ void st_flag(u32* p, u32 v) {
    __hip_atomic_store(p, v, __ATOMIC_RELAXED, __HIP_MEMORY_SCOPE_AGENT);
}
static __device__ __forceinline__ void st_data(float* p, float v) {
    __hip_atomic_store(p, v, __ATOMIC_RELAXED, __HIP_MEMORY_SCOPE_AGENT);
}

__global__ __launch_bounds__(256, 1) void k_fused(
    const float* __restrict__ X, const float* __restrict__ L,
    const float* __restrict__ W1, const float* __restrict__ b1,
    const float* __restrict__ W2, const float* __restrict__ b2,
    const float* __restrict__ theta, float* __restrict__ out,
    float* __restrict__ ws)
{
    float* PB = ws;                    // P(j) = PB + (j-1)*2048

    __shared__ union {
        struct { float Lt[NN * COLS]; float redf[4][16]; float cbv[16]; int rdy[16]; } mv;
        struct { float W1t[64][132]; float redm[16][65]; float wv[64]; } hd;
    } sm;

    const int g = blockIdx.x;   // 256 blocks, 1/CU (LDS-forced); co-residency
    const int t = threadIdx.x;  // proven across r4-r12 regular launches

    if (g < NCHAIN) {
        // ---------------- chain: weff = sum_j c_j (L^T)^j 1 ----------------
        const int u0 = g * COLS;

        if (t <= KDEG) {   // Bernstein -> monomial coefficients (exact binomials)
            const float C10[11] = {1,10,45,120,210,252,210,120,45,10,1};
            float acc = 0.f;
            for (int i = 0; i <= t; ++i) {
                int n = KDEG - i, r = t - i;
                long long cm = 1;
                for (int s = 1; s <= r; ++s) cm = cm * (n - r + s) / s;
                float term = theta[i] * C10[i] * (float)cm;
                if ((t - i) & 1) term = -term;
                acc += term;
            }
            sm.mv.cbv[t] = acc;
        }
        if (t < 16) sm.mv.rdy[t] = 0;

        // L[:, u0:u0+16] -> LDS (128 KB); p_1 (column sums) folded into load
        const float4* L4  = (const float4*)L;
        float4*       Lt4 = (float4*)sm.mv.Lt;
        const int qc = t & 3, r0 = t >> 2;   // fixed quad, 64 row-streams
        {
            float4 acc = make_float4(0.f, 0.f, 0.f, 0.f);
            #pragma unroll 8
            for (int i = 0; i < 32; ++i) {
                int v = r0 + 64 * i;
                float4 lv = L4[(size_t)v * (NN / 4) + (u0 >> 2) + qc];
                Lt4[v * 4 + qc] = lv;
                acc.x += lv.x; acc.y += lv.y; acc.z += lv.z; acc.w += lv.w;
            }
            #pragma unroll
            for (int m = 4; m <= 32; m <<= 1) {
                acc.x += __shfl_xor(acc.x, m); acc.y += __shfl_xor(acc.y, m);
                acc.z += __shfl_xor(acc.z, m); acc.w += __shfl_xor(acc.w, m);
            }
            int lane = t & 63, wid = t >> 6;
            if (lane < 4) *(float4*)&sm.mv.redf[wid][lane * 4] = acc;
        }
        __syncthreads();   // publishes Lt, cbv, rdy-zero, redf(p1)

        float val = 0.f, wacc = 0.f;   // t<16: p_{j-1}[u0+t] and Horner acc
        if (t < COLS) {
            float s = sm.mv.redf[0][t] + sm.mv.redf[1][t]
                    + sm.mv.redf[2][t] + sm.mv.redf[3][t];
            val = s; wacc = sm.mv.cbv[0];              // c_0 * p_0 (p_0 = 1)
            st_data(&PB[u0 + t], s);                   // P(1) = p_1
        }
        if (t < 64) {
            asm volatile("s_waitcnt vmcnt(0)" ::: "memory");
            if (t == 0) st_flag(((u32*)(ws + 28672)) + g * 16, CTAG(1));
        }

        for (int j = 2; j <= KDEG; ++j) {
            // wave 0 polls all 128 flags (2/lane); LDS-relay to waves 1-3
            if (t < 64) {
                const u32* fb = (const u32*)(ws + 28672 + (size_t)(j - 2) * 2048);
                const u32 tag = CTAG(j - 1);
                const u32* f0 = fb + t * 16;
                const u32* f1 = fb + (t + 64) * 16;
                while (!__all(ld_flag(f0) == tag && ld_flag(f1) == tag))
                    __builtin_amdgcn_s_sleep(1);
                asm volatile("" ::: "memory");
                if (t == 0) ((volatile int*)sm.mv.rdy)[j] = 1;
            } else {
                volatile int* vr = (volatile int*)sm.mv.rdy;
                while (vr[j] == 0) __builtin_amdgcn_s_sleep(1);
                asm volatile("" ::: "memory");
            }

            // FMA directly off cached global p_{j-1} (unroll-8: compiler
            // software-pipelines the loads under the FMA stream — r12's
            // full xv[32] batch was part of a +3.6us regression)
            const float* psrc = PB + (size_t)(j - 2) * 2048;
            float4 a2 = make_float4(0.f, 0.f, 0.f, 0.f);
            #pragma unroll 8
            for (int k = 0; k < 32; ++k) {
                int v = r0 + 64 * k;
                float xv = psrc[v];                  // plain, L1/L2-shared
                float4 lv = Lt4[v * 4 + qc];         // conflict-free b128
                a2.x += lv.x * xv; a2.y += lv.y * xv;
                a2.z += lv.z * xv; a2.w += lv.w * xv;
            }
            #pragma unroll
            for (int m = 4; m <= 32; m <<= 1) {
                a2.x += __shfl_xor(a2.x, m); a2.y += __shfl_xor(a2.y, m);
                a2.z += __shfl_xor(a2.z, m); a2.w += __shfl_xor(a2.w, m);
            }
            {
                int lane = t & 63, wid = t >> 6;
                if (lane < 4) *(float4*)&sm.mv.redf[wid][lane * 4] = a2;
            }
            __syncthreads();   // the ONLY barrier in the round

            if (t < COLS) {
                float s = sm.mv.redf[0][t] + sm.mv.redf[1][t]
                        + sm.mv.redf[2][t] + sm.mv.redf[3][t];
                wacc += sm.mv.cbv[j - 1] * val;      // uses register p_{j-1}
                val = s;
                float outv = (j < KDEG) ? s : (wacc + sm.mv.cbv[KDEG] * s);
                st_data(&PB[(size_t)(j - 1) * 2048 + u0 + t], outv);
            }
            if (t < 64) {
                asm volatile("s_waitcnt vmcnt(0)" ::: "memory");
                if (t == 0)
                    st_flag(((u32*)(ws + 28672 + (size_t)(j - 1) * 2048)) + g * 16,
                            CTAG(j));
            }
        }
        return;   // chain done: output is distributed to the head blocks
    }

    // ---------------- head (128 blocks, 2 units each, overlaps chain) --------
    const int u = g - NCHAIN;
    const int vchunk = u & 31, bA = u >> 5, bB = bA + 4;

    // defer X streaming until the chain's L-load is done (CTAG(1) visible)
    if (t == 0) {
        const u32* fp = ((const u32*)(ws + 28672)) + u * 16;
        while (ld_flag(fp) != CTAG(1)) __builtin_amdgcn_s_sleep(2);
    }
    __syncthreads();

    for (int i = t; i < F0D * HIDD; i += 256) {
        int f = i >> 6, h = i & 63;
        sm.hd.W1t[h][f] = W1[i];
    }
    __syncthreads();

    const int hg = t & 15, vg = t >> 4;
    const int vbase = vchunk * 64 + vg * 4;
    const float* XA = X + ((size_t)bA * NN + vbase) * F0D;
    const float* XB = X + ((size_t)bB * NN + vbase) * F0D;
    float accA[4][4] = {}, accB[4][4] = {};
    for (int f = 0; f < F0D; f += 4) {
        float4 xa[4], xb[4];
        #pragma unroll
        for (int i = 0; i < 4; ++i) {
            xa[i] = *(const float4*)(XA + (size_t)i * F0D + f);
            xb[i] = *(const float4*)(XB + (size_t)i * F0D + f);
        }
        #pragma unroll
        for (int jj = 0; jj < 4; ++jj) {
            float4 wr = *(const float4*)(&sm.hd.W1t[hg + 16 * jj][f]);
            #pragma unroll
            for (int i = 0; i < 4; ++i) {
                accA[i][jj] += xa[i].x * wr.x + xa[i].y * wr.y
                             + xa[i].z * wr.z + xa[i].w * wr.w;
                accB[i][jj] += xb[i].x * wr.x + xb[i].y * wr.y
                             + xb[i].z * wr.z + xb[i].w * wr.w;
            }
        }
    }

    // weff: poll ONLY our 4 producer-block flags (level KDEG), then plain-load
    if (t < 4) {
        const u32* fp = ((u32*)(ws + 28672 + (size_t)(KDEG - 1) * 2048))
                      + (vchunk * 4 + t) * 16;
        while (ld_flag(fp) != CTAG(KDEG)) __builtin_amdgcn_s_sleep(2);
        asm volatile("" ::: "memory");
    }
    __syncthreads();
    if (t < 16)
        ((float4*)sm.hd.wv)[t] =
            ((const float4*)(PB + (size_t)(KDEG - 1) * 2048 + vchunk * 64))[t];
    __syncthreads();

    const float inv = 1.0f / (float)NN;
    float hsA[4] = {0.f,0.f,0.f,0.f}, hsB[4] = {0.f,0.f,0.f,0.f};
    #pragma unroll
    for (int i = 0; i < 4; ++i) {
        float we = sm.hd.wv[vg * 4 + i];
        #pragma unroll
        for (int jj = 0; jj < 4; ++jj) {
            float rA = accA[i][jj] + b1[hg + 16 * jj];
            float rB = accB[i][jj] + b1[hg + 16 * jj];
            rA = rA > 0.f ? rA : 0.f;
            rB = rB > 0.f ? rB : 0.f;
            hsA[jj] += rA * we;
            hsB[jj] += rB * we;
        }
    }

    // distributed output epilogue: fold partials through W2 locally,
    // atomicAdd into memset-zeroed d_out (no flags, no Hg, no block-0 tail)
    #pragma unroll
    for (int jj = 0; jj < 4; ++jj) sm.hd.redm[vg][hg + 16 * jj] = hsA[jj];
    __syncthreads();
    if (t < 64) {
        float s = 0.f;
        #pragma unroll
        for (int i = 0; i < 16; ++i) s += sm.hd.redm[i][t];
        sm.hd.wv[t] = s * inv;       // wv free: weff already consumed
    }
    __syncthreads();
    if (t < 16) {
        float po = 0.f;
        #pragma unroll
        for (int h = 0; h < HIDD; ++h) po += sm.hd.wv[h] * W2[h * 16 + t];
        if (vchunk == 0) po += b2[t];
        atomicAdd(&out[bA * 16 + t], po);
    }
    #pragma unroll
    for (int jj = 0; jj < 4; ++jj) sm.hd.redm[vg][hg + 16 * jj] = hsB[jj];
    __syncthreads();                 // also orders t<16's wv reads above
    if (t < 64) {
        float s = 0.f;
        #pragma unroll
        for (int i = 0; i < 16; ++i) s += sm.hd.redm[i][t];
        sm.hd.wv[t] = s * inv;
    }
    __syncthreads();
    if (t < 16) {
        float po = 0.f;
        #pragma unroll
        for (int h = 0; h < HIDD; ++h) po += sm.hd.wv[h] * W2[h * 16 + t];
        if (vchunk == 0) po += b2[t];
        atomicAdd(&out[bB * 16 + t], po);
    }
}

extern "C" void kernel_launch(void* const* d_in, const int* in_sizes, int n_in,
                              void* d_out, int out_size, void* d_ws, size_t ws_size,
                              hipStream_t stream) {
    const float* X     = (const float*)d_in[0];
    const float* L     = (const float*)d_in[1];
    const float* W1    = (const float*)d_in[2];
    const float* b1    = (const float*)d_in[3];
    const float* W2    = (const float*)d_in[4];
    const float* b2    = (const float*)d_in[5];
    const float* theta = (const float*)d_in[6];
    // d_in[7] = dp = 0 -> dropout identity; ignored.
    float* outp = (float*)d_out;
    float* wsp  = (float*)d_ws;

    // out is accumulated via atomicAdd -> zero it (512 B)
    hipMemsetAsync(d_out, 0, out_size, stream);

    hipLaunchKernelGGL(k_fused, dim3(256), dim3(256), 0, stream,
                       X, L, W1, b1, W2, b2, theta, outp, wsp);
}